// Round 1
// baseline (848.008 us; speedup 1.0000x reference)
//
#include <hip/hip_runtime.h>

// SelfTensorProductS2Grid: out[n,i,c] = sum_g Wf[g,i] * (sum_j Wt[g,j] * x[n,j,c])^2
// N=4096, L2=49, C=128, RES=18 -> G=324 grid points.
// fp32 vector baseline (no fp32 MFMA on CDNA4). Compute-bound: ~33.5 GFLOP,
// fp32-vector roofline ~213 us.

#define NN   4096
#define L2   49
#define CC   128
#define RESB 18
#define GG_TOT (RESB * RESB)   // 324
#define G_PER_H (GG_TOT / 2)   // 162
#define GGRP 6                 // grid points per inner pass (162 % 6 == 0)

__global__ __launch_bounds__(256, 3)
void stp_s2grid_kernel(const float* __restrict__ inp,
                       const float* __restrict__ Wt,
                       const float* __restrict__ Wf,
                       float* __restrict__ out)
{
    __shared__ float Xs[L2 * CC];     // 25088 B: inputs[n] staged
    __shared__ float Os[L2 * CC];     // 25088 B: cross-half reduction

    const int tid = threadIdx.x;
    const int n   = blockIdx.x;

    // ---- stage X = inputs[n] (49x128 fp32) into LDS, float4-coalesced ----
    {
        const float4* src = (const float4*)(inp + (size_t)n * (L2 * CC));
        float4* dst = (float4*)Xs;
        #pragma unroll
        for (int idx = tid; idx < (L2 * CC) / 4; idx += 256)
            dst[idx] = src[idx];
    }
    __syncthreads();

    const int c = tid & (CC - 1);   // lane-contiguous channel
    const int h = tid >> 7;         // which half of the grid-point range

    float acc[L2];
    #pragma unroll
    for (int i = 0; i < L2; ++i) acc[i] = 0.0f;

    const int g_begin = h * G_PER_H;
    for (int g0 = g_begin; g0 < g_begin + G_PER_H; g0 += GGRP) {
        // g0 is uniform within each wave (h is wave-uniform); force scalar path
        const int gu = __builtin_amdgcn_readfirstlane(g0);
        const float* __restrict__ wt = Wt + gu * L2;
        const float* __restrict__ wf = Wf + gu * L2;

        // v[k] = sum_i Wt[g0+k, i] * X[i, c]  -- one LDS read feeds GGRP FMAs
        float v[GGRP];
        #pragma unroll
        for (int k = 0; k < GGRP; ++k) v[k] = 0.0f;

        #pragma unroll
        for (int i = 0; i < L2; ++i) {
            const float x = Xs[i * CC + c];
            #pragma unroll
            for (int k = 0; k < GGRP; ++k)
                v[k] = fmaf(wt[k * L2 + i], x, v[k]);
        }

        // square, then acc[i] += Wf[g0+k, i] * v[k]^2
        float v2[GGRP];
        #pragma unroll
        for (int k = 0; k < GGRP; ++k) v2[k] = v[k] * v[k];

        #pragma unroll
        for (int i = 0; i < L2; ++i) {
            #pragma unroll
            for (int k = 0; k < GGRP; ++k)
                acc[i] = fmaf(wf[k * L2 + i], v2[k], acc[i]);
        }
    }

    // ---- reduce the two halves through LDS, store coalesced ----
    if (h == 1) {
        #pragma unroll
        for (int i = 0; i < L2; ++i) Os[i * CC + c] = acc[i];
    }
    __syncthreads();
    if (h == 0) {
        float* __restrict__ o = out + (size_t)n * (L2 * CC);
        #pragma unroll
        for (int i = 0; i < L2; ++i)
            o[i * CC + c] = acc[i] + Os[i * CC + c];
    }
}

extern "C" void kernel_launch(void* const* d_in, const int* in_sizes, int n_in,
                              void* d_out, int out_size, void* d_ws, size_t ws_size,
                              hipStream_t stream) {
    const float* inp = (const float*)d_in[0];   // (4096, 49, 128) fp32
    const float* Wt  = (const float*)d_in[1];   // (18, 18, 49) fp32
    const float* Wf  = (const float*)d_in[2];   // (18, 18, 49) fp32
    float* out = (float*)d_out;                 // (4096, 49, 128) fp32

    stp_s2grid_kernel<<<NN, 256, 0, stream>>>(inp, Wt, Wf, out);
}

// Round 2
// 338.682 us; speedup vs baseline: 2.5038x; 2.5038x over previous
//
#include <hip/hip_runtime.h>

// SelfTensorProductS2Grid via bf16 MFMA (16x16x32), fused per-sample:
//   grid[g,c] = sum_i Wt[g,i] X[i,c];  out[i,c] = sum_g Wf[g,i] grid[g,c]^2
// N=4096, L2=49 (pad K->64), C=128 (two halves of 64), G=324 (pad M->336, K->352).
// W matrices pre-swizzled into MFMA-fragment-major bf16 arrays in d_ws by a
// prep kernel each call (ws re-poisoned by harness): every A-frag load is one
// coalesced global_load_dwordx4 from L2.

#define NN    4096
#define L2D   49
#define CCH   128
#define GTOT  324
#define MT1   21              // stage1 M-tiles over g: 21*16 = 336
#define KC2   11              // stage2 K-chunks over g: 11*32 = 352

typedef __attribute__((ext_vector_type(8))) short bf16x8;
typedef __attribute__((ext_vector_type(4))) float f32x4;

#define XS_STRIDE 72          // shorts per Xs row: 144 B (16B-aligned), 36 dw
#define WT_ELEMS (MT1 * 2 * 64 * 8)   // 21504 bf16
#define WF_ELEMS (4 * KC2 * 64 * 8)   // 22528 bf16

__device__ __forceinline__ short f2bf(float f) {
    union { float f; unsigned u; } x; x.f = f;
    return (short)((x.u + 0x7fffu + ((x.u >> 16) & 1u)) >> 16);   // RNE
}

// ---- prep: swizzle Wt/Wf (fp32, g-major [g][i]) into fragment-major bf16 ----
// WtF[mt][kc][lane][j]: A[m=g=mt*16+(lane&15)][k=i=kc*32+(lane>>4)*8+j]
// WfF[it][kc][lane][j]: A[m=i=it*16+(lane&15)][k=g=kc*32+(lane>>4)*8+j]
__global__ void prep_w_kernel(const float* __restrict__ Wt,
                              const float* __restrict__ Wf,
                              short* __restrict__ WtF,
                              short* __restrict__ WfF)
{
    int idx = blockIdx.x * 256 + threadIdx.x;
    if (idx < WT_ELEMS) {
        int j = idx & 7, lane = (idx >> 3) & 63, kc = (idx >> 9) & 1, mt = idx >> 10;
        int g = mt * 16 + (lane & 15);
        int i = kc * 32 + (lane >> 4) * 8 + j;
        float v = (g < GTOT && i < L2D) ? Wt[g * L2D + i] : 0.0f;
        WtF[idx] = f2bf(v);
    } else {
        int e = idx - WT_ELEMS;
        if (e < WF_ELEMS) {
            int j = e & 7, lane = (e >> 3) & 63;
            int t = e >> 9;
            int kc = t % KC2, it = t / KC2;
            int i = it * 16 + (lane & 15);
            int g = kc * 32 + (lane >> 4) * 8 + j;
            float v = (g < GTOT && i < L2D) ? Wf[g * L2D + i] : 0.0f;
            WfF[e] = f2bf(v);
        }
    }
}

__global__ __launch_bounds__(256, 2)
void stp_mfma_kernel(const float* __restrict__ inp,
                     const short* __restrict__ WtF,
                     const short* __restrict__ WfF,
                     float* __restrict__ out)
{
    __shared__ __align__(16) short Xs[CCH * XS_STRIDE];    // 18432 B
    __shared__ __align__(16) short Gs[KC2 * 4 * 64 * 8];   // 45056 B (grid^2, frag-major)

    const int tid  = threadIdx.x;
    const int n    = blockIdx.x;
    const int lane = tid & 63;
    const int wave = tid >> 6;
    const int lm   = lane & 15;
    const int quad = lane >> 4;

    // ---- stage Xs[c][i] = bf16(X[i][c]); zero-pad i in [49,64) ----
    {
        const float* Xn = inp + (size_t)n * (L2D * CCH);
        int c = tid & 127;
        for (int i = tid >> 7; i < 64; i += 2) {
            float v = (i < L2D) ? Xn[i * CCH + c] : 0.0f;
            Xs[c * XS_STRIDE + i] = f2bf(v);
        }
    }
    // ---- zero Gs tail (kc=10, lane' in [32,64) i.e. g in [336,352)) ----
    {
        int e = tid * 4;                 // 1024 shorts total
        int nt = e >> 8, off = e & 255;
        short4 z; z.x = 0; z.y = 0; z.z = 0; z.w = 0;
        *(short4*)&Gs[((40 + nt) * 64 + 32) * 8 + off] = z;
    }
    __syncthreads();

    const int nt0   = (wave & 1) * 2;            // wave's two N-tiles (of 4 per half)
    const int mt_lo = (wave >> 1) ? 11 : 0;      // wave-pair's M-tile range
    const int mt_hi = (wave >> 1) ? 21 : 11;

    for (int h = 0; h < 2; ++h) {
        // ================= stage 1: grid = Wt * X, square, to Gs =================
        bf16x8 Bf[2][2];
        #pragma unroll
        for (int t = 0; t < 2; ++t)
            #pragma unroll
            for (int kc = 0; kc < 2; ++kc) {
                int c = h * 64 + (nt0 + t) * 16 + lm;
                int i = kc * 32 + quad * 8;
                Bf[t][kc] = *(const bf16x8*)&Xs[c * XS_STRIDE + i];
            }
        for (int mt = mt_lo; mt < mt_hi; ++mt) {
            bf16x8 Af0 = *(const bf16x8*)&WtF[((mt * 2 + 0) * 64 + lane) * 8];
            bf16x8 Af1 = *(const bf16x8*)&WtF[((mt * 2 + 1) * 64 + lane) * 8];
            int gbase = mt * 16 + quad * 4;      // 4 consecutive g rows (regs 0..3)
            int kcg = gbase >> 5;
            int g5  = gbase & 31;
            int lp  = (g5 >> 3) * 16 + lm;       // lane' in destination fragment
            int jj  = g5 & 7;                    // 0 or 4
            #pragma unroll
            for (int t = 0; t < 2; ++t) {
                f32x4 acc = {0.0f, 0.0f, 0.0f, 0.0f};
                acc = __builtin_amdgcn_mfma_f32_16x16x32_bf16(Af0, Bf[t][0], acc, 0, 0, 0);
                acc = __builtin_amdgcn_mfma_f32_16x16x32_bf16(Af1, Bf[t][1], acc, 0, 0, 0);
                short4 q;
                q.x = f2bf(acc[0] * acc[0]);
                q.y = f2bf(acc[1] * acc[1]);
                q.z = f2bf(acc[2] * acc[2]);
                q.w = f2bf(acc[3] * acc[3]);
                *(short4*)&Gs[((kcg * 4 + (nt0 + t)) * 64 + lp) * 8 + jj] = q;
            }
        }
        __syncthreads();

        // ================= stage 2: out = WfT * grid^2 =================
        f32x4 acc2[4];
        #pragma unroll
        for (int t = 0; t < 4; ++t) acc2[t] = (f32x4){0.0f, 0.0f, 0.0f, 0.0f};
        for (int kc = 0; kc < KC2; ++kc) {
            bf16x8 Af = *(const bf16x8*)&WfF[((wave * KC2 + kc) * 64 + lane) * 8];
            #pragma unroll
            for (int t = 0; t < 4; ++t) {
                bf16x8 Bg = *(const bf16x8*)&Gs[((kc * 4 + t) * 64 + lane) * 8];
                acc2[t] = __builtin_amdgcn_mfma_f32_16x16x32_bf16(Af, Bg, acc2[t], 0, 0, 0);
            }
        }
        {
            float* On = out + (size_t)n * (L2D * CCH);
            int ib = wave * 16 + quad * 4;
            #pragma unroll
            for (int t = 0; t < 4; ++t) {
                int c = h * 64 + t * 16 + lm;
                #pragma unroll
                for (int r = 0; r < 4; ++r) {
                    int i = ib + r;
                    if (i < L2D) On[i * CCH + c] = acc2[t][r];
                }
            }
        }
        __syncthreads();   // protect Gs before next half's stage-1 writes
    }
}

extern "C" void kernel_launch(void* const* d_in, const int* in_sizes, int n_in,
                              void* d_out, int out_size, void* d_ws, size_t ws_size,
                              hipStream_t stream) {
    const float* inp = (const float*)d_in[0];   // (4096, 49, 128) fp32
    const float* Wt  = (const float*)d_in[1];   // (18, 18, 49)  fp32 -> g = b*18+a
    const float* Wf  = (const float*)d_in[2];   // (18, 18, 49)  fp32
    float* out = (float*)d_out;                 // (4096, 49, 128) fp32

    short* WtF = (short*)d_ws;                  // 43008 B
    short* WfF = WtF + WT_ELEMS;                // 45056 B  (total 88064 B of ws)

    const int prep_threads = WT_ELEMS + WF_ELEMS;   // 44032
    prep_w_kernel<<<(prep_threads + 255) / 256, 256, 0, stream>>>(Wt, Wf, WtF, WfF);
    stp_mfma_kernel<<<NN, 256, 0, stream>>>(inp, WtF, WfF, out);
}

// Round 3
// 214.301 us; speedup vs baseline: 3.9571x; 1.5804x over previous
//
#include <hip/hip_runtime.h>

// SelfTensorProductS2Grid via bf16 MFMA (16x16x32), fully register-resident:
//   grid[g,c] = sum_i Wt[g,i] X[i,c];  out[i,c] = sum_g Wf[g,i] grid[g,c]^2
// g is an internal contraction index -> relabel it so stage-1's C/D layout
// (g = tile*16 + quad*4 + r) IS stage-2's B-operand layout
// (g = chunk*32 + quad*8 + j, with j>=4 taken from the odd tile). The
// permutation is baked into the WfF prep. No LDS, no barriers, one wave per
// (n, c-half) task; W fragments live in L2 (~90 KB).

#define NN    4096
#define L2D   49
#define CCH   128
#define GTOT  324
#define MT1P  22              // stage-1 g-tiles of 16 (21 real + 1 zero pad)
#define KC2   11              // stage-2 g-chunks of 32

typedef __attribute__((ext_vector_type(8))) short bf16x8;
typedef __attribute__((ext_vector_type(4))) float f32x4;

#define WT_SHORTS (MT1P * 2 * 64 * 8)   // 22528
#define WF_SHORTS (4 * KC2 * 64 * 8)    // 22528

__device__ __forceinline__ short f2bf(float f) {
    union { float f; unsigned u; } x; x.f = f;
    return (short)((x.u + 0x7fffu + ((x.u >> 16) & 1u)) >> 16);   // RNE
}

// WtF[mt][kcx][lane][j]: A[m=g=mt*16+(lane&15)][k=i=kcx*32+(lane>>4)*8+j]
// WfF[it][kc2][lane][j]: A[m=i=it*16+(lane&15)][k=glog], where
//   gphys(glog) = kc2*32 + (j>>2)*16 + (lane>>4)*4 + (j&3)   <-- the relabel
__global__ void prep_w_kernel(const float* __restrict__ Wt,
                              const float* __restrict__ Wf,
                              short* __restrict__ WtF,
                              short* __restrict__ WfF)
{
    int idx = blockIdx.x * 256 + threadIdx.x;
    if (idx < WT_SHORTS) {
        int j = idx & 7, lane = (idx >> 3) & 63, kcx = (idx >> 9) & 1, mt = idx >> 10;
        int g = mt * 16 + (lane & 15);
        int i = kcx * 32 + (lane >> 4) * 8 + j;
        WtF[idx] = f2bf((g < GTOT && i < L2D) ? Wt[g * L2D + i] : 0.0f);
    } else if (idx < WT_SHORTS + WF_SHORTS) {
        int e = idx - WT_SHORTS;
        int j = e & 7, lane = (e >> 3) & 63, t = e >> 9;
        int kc2 = t % KC2, it = t / KC2;
        int i = it * 16 + (lane & 15);
        int g = kc2 * 32 + (j >> 2) * 16 + (lane >> 4) * 4 + (j & 3);
        WfF[e] = f2bf((g < GTOT && i < L2D) ? Wf[g * L2D + i] : 0.0f);
    }
}

__global__ __launch_bounds__(256, 3)
void stp_mfma2_kernel(const float* __restrict__ inp,
                      const short* __restrict__ WtF,
                      const short* __restrict__ WfF,
                      float* __restrict__ out)
{
    const int tid  = threadIdx.x;
    const int lane = tid & 63;
    const int wave = tid >> 6;
    const int lm   = lane & 15;
    const int quad = lane >> 4;

    const int task = blockIdx.x * 4 + wave;   // 8192 tasks = (n, c-half)
    const int n    = task >> 1;
    const int h    = task & 1;

    const float* __restrict__ Xn = inp + (size_t)n * (L2D * CCH);

    // ---- X B-fragments straight from global: B[k=i][n=c] ----
    // lane holds c = h*64 + t*16 + lm ; i = kcx*32 + quad*8 + j
    bf16x8 Bx[4][2];
    #pragma unroll
    for (int t = 0; t < 4; ++t) {
        const int c = h * 64 + t * 16 + lm;
        #pragma unroll
        for (int kcx = 0; kcx < 2; ++kcx) {
            bf16x8 b;
            #pragma unroll
            for (int j = 0; j < 8; ++j) {
                const int i = kcx * 32 + quad * 8 + j;
                float v = 0.0f;
                if (i < L2D) v = Xn[i * CCH + c];
                b[j] = f2bf(v);
            }
            Bx[t][kcx] = b;
        }
    }

    f32x4 acc2[4][4];
    #pragma unroll
    for (int it = 0; it < 4; ++it)
        #pragma unroll
        for (int t = 0; t < 4; ++t)
            acc2[it][t] = (f32x4){0.0f, 0.0f, 0.0f, 0.0f};

    #pragma unroll 1
    for (int kc2 = 0; kc2 < KC2; ++kc2) {
        // W fragments for this g-chunk (all 16B coalesced, L2-resident)
        bf16x8 Wtf[2][2];
        #pragma unroll
        for (int tt = 0; tt < 2; ++tt)
            #pragma unroll
            for (int kcx = 0; kcx < 2; ++kcx)
                Wtf[tt][kcx] = *(const bf16x8*)&WtF[(((2 * kc2 + tt) * 2 + kcx) * 64 + lane) * 8];
        bf16x8 Wff[4];
        #pragma unroll
        for (int it = 0; it < 4; ++it)
            Wff[it] = *(const bf16x8*)&WfF[((it * KC2 + kc2) * 64 + lane) * 8];

        #pragma unroll
        for (int t = 0; t < 4; ++t) {
            // stage 1: two 16-row g-tiles -> C-layout regs = B-frag halves
            bf16x8 Bg;
            #pragma unroll
            for (int tt = 0; tt < 2; ++tt) {
                f32x4 gacc = (f32x4){0.0f, 0.0f, 0.0f, 0.0f};
                gacc = __builtin_amdgcn_mfma_f32_16x16x32_bf16(Wtf[tt][0], Bx[t][0], gacc, 0, 0, 0);
                gacc = __builtin_amdgcn_mfma_f32_16x16x32_bf16(Wtf[tt][1], Bx[t][1], gacc, 0, 0, 0);
                #pragma unroll
                for (int r = 0; r < 4; ++r)
                    Bg[tt * 4 + r] = f2bf(gacc[r] * gacc[r]);
            }
            // stage 2: accumulate out[i, c] over this g-chunk
            #pragma unroll
            for (int it = 0; it < 4; ++it)
                acc2[it][t] = __builtin_amdgcn_mfma_f32_16x16x32_bf16(Wff[it], Bg, acc2[it][t], 0, 0, 0);
        }
    }

    // ---- store: C/D layout col=c=lm, row=i=it*16+quad*4+r ----
    float* __restrict__ On = out + (size_t)n * (L2D * CCH);
    #pragma unroll
    for (int it = 0; it < 4; ++it) {
        #pragma unroll
        for (int t = 0; t < 4; ++t) {
            const int c = h * 64 + t * 16 + lm;
            #pragma unroll
            for (int r = 0; r < 4; ++r) {
                const int i = it * 16 + quad * 4 + r;
                if (i < L2D) On[i * CCH + c] = acc2[it][t][r];
            }
        }
    }
}

extern "C" void kernel_launch(void* const* d_in, const int* in_sizes, int n_in,
                              void* d_out, int out_size, void* d_ws, size_t ws_size,
                              hipStream_t stream) {
    const float* inp = (const float*)d_in[0];   // (4096, 49, 128) fp32
    const float* Wt  = (const float*)d_in[1];   // (18*18, 49) fp32
    const float* Wf  = (const float*)d_in[2];   // (18*18, 49) fp32
    float* out = (float*)d_out;                 // (4096, 49, 128) fp32

    short* WtF = (short*)d_ws;
    short* WfF = WtF + WT_SHORTS;               // total 90112 B of ws

    const int prep_threads = WT_SHORTS + WF_SHORTS;   // 45056
    prep_w_kernel<<<(prep_threads + 255) / 256, 256, 0, stream>>>(Wt, Wf, WtF, WfF);
    stp_mfma2_kernel<<<2048, 256, 0, stream>>>(inp, WtF, WfF, out);
}